// Round 23
// baseline (60.605 us; speedup 1.0000x reference)
//
#include <hip/hip_runtime.h>

#define EPSF 1e-12f

__device__ __forceinline__ unsigned short f2bf(float f) {
  unsigned int u = __float_as_uint(f);
  unsigned int r = u + 0x7fffu + ((u >> 16) & 1u);  // RNE
  return (unsigned short)(r >> 16);
}
#define BFLO(u) __uint_as_float((u) << 16)
#define BFHI(u) __uint_as_float((u) & 0xffff0000u)

// ---------------------------------------------------------------------------
// Kernel 1: partial G slices (split-K). grid (n/64, n/64, S), block 256.
// ---------------------------------------------------------------------------
__global__ void gemm_tile(const float* __restrict__ F, float* __restrict__ Gout,
                          int n, int d, int kchunk) {
  __shared__ float As[64][36];
  __shared__ float Bs[64][36];
  const int tid = threadIdx.x;
  const int bx = blockIdx.x, by = blockIdx.y, kz = blockIdx.z;
  const int ty = tid >> 4, tx = tid & 15;
  const int lrow = tid >> 2;
  const int lcol = (tid & 3) * 8;
  const float* Ap = F + (size_t)(bx * 64 + lrow) * d + (size_t)kz * kchunk + lcol;
  const float* Bp = F + (size_t)(by * 64 + lrow) * d + (size_t)kz * kchunk + lcol;
  float acc[4][4];
  for (int r = 0; r < 4; r++)
    for (int c = 0; c < 4; c++) acc[r][c] = 0.0f;

  for (int ks = 0; ks < kchunk; ks += 32) {
    float4 a0 = *(const float4*)(Ap + ks);
    float4 a1 = *(const float4*)(Ap + ks + 4);
    float4 b0 = *(const float4*)(Bp + ks);
    float4 b1 = *(const float4*)(Bp + ks + 4);
    __syncthreads();
    *(float4*)&As[lrow][lcol]     = a0;
    *(float4*)&As[lrow][lcol + 4] = a1;
    *(float4*)&Bs[lrow][lcol]     = b0;
    *(float4*)&Bs[lrow][lcol + 4] = b1;
    __syncthreads();
#pragma unroll
    for (int kk = 0; kk < 32; kk += 4) {
      float4 av[4], bv[4];
#pragma unroll
      for (int r = 0; r < 4; r++) av[r] = *(const float4*)&As[ty + 16 * r][kk];
#pragma unroll
      for (int c = 0; c < 4; c++) bv[c] = *(const float4*)&Bs[tx + 16 * c][kk];
#pragma unroll
      for (int r = 0; r < 4; r++) {
        float4 A = av[r];
#pragma unroll
        for (int c = 0; c < 4; c++) {
          float4 B = bv[c];
          acc[r][c] += A.x * B.x + A.y * B.y + A.z * B.z + A.w * B.w;
        }
      }
    }
  }
  float* Gs = Gout + (size_t)kz * n * n;
#pragma unroll
  for (int r = 0; r < 4; r++)
#pragma unroll
    for (int c = 0; c < 4; c++)
      Gs[(size_t)(bx * 64 + ty + 16 * r) * n + (by * 64 + tx + 16 * c)] =
          acc[r][c];
}

// ---------------------------------------------------------------------------
// Kernel 2: fused slice-reduce + stats (r18-validated form). grid 64 x 256.
// Per row r: sum S slices -> write G row; accuracy flag; LSE[r][id] table.
// ---------------------------------------------------------------------------
__global__ void stats_kernel(const float* __restrict__ Gp,
                             const int* __restrict__ targets,
                             float* __restrict__ G, float* __restrict__ LSEtab,
                             float* __restrict__ flags, int n, int S) {
  __shared__ float bins[4][33];
  __shared__ int tg[256];
  __shared__ float diag[256];
  const int tid = threadIdx.x;
  const int lane = tid & 63;
  const int w = tid >> 6;
  const int nn = n * n;
  tg[tid] = targets[tid];
  {
    float s0 = 0.0f;
    for (int s = 0; s < S; s++)
      s0 += Gp[(size_t)s * nn + (size_t)tid * (n + 1)];
    diag[tid] = s0;
  }
  if (tid < 128) bins[tid >> 5][tid & 31] = 0.0f;
  __syncthreads();

  const int r = blockIdx.x * 4 + w;
  const int nhalf = n >> 1;
  const int opp0 = (r < nhalf) ? nhalf : 0;
  const int myid = tg[r];
  const float sqr = diag[r];

  // reduce row r across slices (each lane owns 4 cols), write G
  float4 v = make_float4(0.f, 0.f, 0.f, 0.f);
  for (int s = 0; s < S; s++) {
    float4 t = *(const float4*)(Gp + (size_t)s * nn + (size_t)r * n + lane * 4);
    v.x += t.x; v.y += t.y; v.z += t.z; v.w += t.w;
  }
  *(float4*)(G + (size_t)r * n + lane * 4) = v;
  float gv[4] = {v.x, v.y, v.z, v.w};

  float dap = -1e30f, dan = 1e30f;
#pragma unroll
  for (int q = 0; q < 4; q++) {
    int j = lane * 4 + q;
    float dist = sqrtf(fmaxf(sqr + diag[j] - 2.0f * gv[q], EPSF));
    if (tg[j] == myid) dap = fmaxf(dap, dist);
    else               dan = fminf(dan, dist);
  }
#pragma unroll
  for (int off = 32; off; off >>= 1) {
    dap = fmaxf(dap, __shfl_xor(dap, off));
    dan = fminf(dan, __shfl_xor(dan, off));
  }
  if (lane == 0) flags[r] = (dan >= dap) ? 1.0f : 0.0f;

  float mx = -1e30f;
#pragma unroll
  for (int q = 0; q < 4; q++) {
    int j = lane * 4 + q;
    if (j >= opp0 && j < opp0 + nhalf) mx = fmaxf(mx, gv[q]);
  }
#pragma unroll
  for (int off = 32; off; off >>= 1) mx = fmaxf(mx, __shfl_xor(mx, off));

#pragma unroll
  for (int q = 0; q < 4; q++) {
    int j = lane * 4 + q;
    if (j >= opp0 && j < opp0 + nhalf)
      atomicAdd(&bins[w][tg[j]], __expf(gv[q] - mx));
  }
  __syncthreads();

  if (lane < 32) {
    float b = bins[w][lane];
    float lv = __shfl_up(b, 1, 32);
    if (lane == 0) lv = 0.0f;
#pragma unroll
    for (int off = 1; off < 32; off <<= 1) {
      float t = __shfl_up(lv, off, 32);
      if (lane >= off) lv += t;
    }
    float rv = __shfl_down(b, 1, 32);
    if (lane == 31) rv = 0.0f;
#pragma unroll
    for (int off = 1; off < 32; off <<= 1) {
      float t = __shfl_down(rv, off, 32);
      if (lane + off < 32) rv += t;
    }
    float excl = fmaxf(lv + rv, 1e-37f);
    LSEtab[(size_t)r * 32 + lane] = mx + __logf(excl);  // [row][id]
  }
}

// ---------------------------------------------------------------------------
// Kernel 3: class-dedup loss (r16/r22-validated). grid (64, 8), block 256.
// ---------------------------------------------------------------------------
__global__ __launch_bounds__(256, 2) void TransitionLoss_30666066494151_kernel(
    const float* __restrict__ G, const int* __restrict__ targets,
    const float* __restrict__ LSEtab, float* __restrict__ lsp,
    float* __restrict__ lan, float* __restrict__ cnts, int n) {
  __shared__ unsigned short W[128][136];   // 34816 B bf16
  __shared__ int tg[256];
  __shared__ int maskA[128], maskB[128];
  __shared__ float Ri[128], Cl[128];
  __shared__ float SMRAW[16][17];
  __shared__ float SP[16][17], SQ[16][17];
  __shared__ float red[256];
  __shared__ int Plist[16], Qlist[16];
  __shared__ int ctrP, ctrQ;

  const int tid = threadIdx.x;
  const int cls = blockIdx.x;
  const int part = blockIdx.y;      // 0..7 -> rows [part*16, part*16+16)
  const int nhalf = n >> 1;
  const int myid = cls & 31;
  const int hA = cls >> 5;
  const int rowA0 = hA * nhalf;
  const int colB0 = nhalf - rowA0;

  tg[tid] = targets[tid];
  if (tid == 0) { ctrP = 0; ctrQ = 0; }
  __syncthreads();

  if (tid < 128) {
    maskA[tid] = (tg[rowA0 + tid] != myid) ? 1 : 0;
    Ri[tid] = LSEtab[(size_t)(rowA0 + tid) * 32 + myid];
  } else {
    maskB[tid - 128] = (tg[colB0 + tid - 128] != myid) ? 1 : 0;
    Cl[tid - 128] = LSEtab[(size_t)(colB0 + tid - 128) * 32 + myid];
  }
  if (tg[tid] == myid) {
    int inAhalf = (((tid >= nhalf) ? 1 : 0) == hA) ? 1 : 0;
    if (inAhalf) { int k = atomicAdd(&ctrP, 1); if (k < 16) Plist[k] = tid; }
    else         { int k = atomicAdd(&ctrQ, 1); if (k < 16) Qlist[k] = tid; }
  }
  __syncthreads();
  const int nP = min(ctrP, 16), nQ = min(ctrQ, 16);

  // Fused load + W fill (bf16): 16 float4, 8 in flight per group.
#pragma unroll
  for (int k8 = 0; k8 < 2; k8++) {
    float4 g[8];
#pragma unroll
    for (int u = 0; u < 8; u++) {
      int e4 = tid + 256 * (k8 * 8 + u);
      int i = e4 >> 5;
      int l4 = (e4 & 31) << 2;
      g[u] = *(const float4*)(G + (size_t)(rowA0 + i) * n + colB0 + l4);
    }
#pragma unroll
    for (int u = 0; u < 8; u++) {
      int e4 = tid + 256 * (k8 * 8 + u);
      int i = e4 >> 5;
      int l4 = (e4 & 31) << 2;
      float rih = 0.5f * Ri[i];
      int ma = maskA[i];
      float w0 = (ma && maskB[l4 + 0]) ? __expf(g[u].x - rih - 0.5f * Cl[l4 + 0]) : 0.0f;
      float w1 = (ma && maskB[l4 + 1]) ? __expf(g[u].y - rih - 0.5f * Cl[l4 + 1]) : 0.0f;
      float w2 = (ma && maskB[l4 + 2]) ? __expf(g[u].z - rih - 0.5f * Cl[l4 + 2]) : 0.0f;
      float w3 = (ma && maskB[l4 + 3]) ? __expf(g[u].w - rih - 0.5f * Cl[l4 + 3]) : 0.0f;
      uint2 packed;
      packed.x = (unsigned)f2bf(w0) | ((unsigned)f2bf(w1) << 16);
      packed.y = (unsigned)f2bf(w2) | ((unsigned)f2bf(w3) << 16);
      *(uint2*)&W[i][l4] = packed;
    }
  }

  // t_pos parallel gather (part 0 only): one latency round.
  if (part == 0) {
    int p = tid >> 4, q = tid & 15;
    float v = 0.0f;
    if (p < nP && q < nQ) v = G[(size_t)Plist[p] * n + Qlist[q]];
    SMRAW[p][q] = v;
  }
  __syncthreads();

  // SYRK: rows [part*16 .. +16) x 128 cols, K=128 bf16 from LDS.
  const int i0 = part * 16;
  const int ty = tid >> 4, tx = tid & 15;
  const float riA = Ri[i0 + ty];
  float acc[8];
#pragma unroll
  for (int c = 0; c < 8; c++) acc[c] = 0.0f;

  for (int kk = 0; kk < 128; kk += 8) {
    uint4 ar = *(const uint4*)&W[i0 + ty][kk];
    uint4 br[8];
#pragma unroll
    for (int c = 0; c < 8; c++) br[c] = *(const uint4*)&W[tx + 16 * c][kk];
    float a0 = BFLO(ar.x), a1 = BFHI(ar.x), a2 = BFLO(ar.y), a3 = BFHI(ar.y);
    float a4 = BFLO(ar.z), a5 = BFHI(ar.z), a6 = BFLO(ar.w), a7 = BFHI(ar.w);
#pragma unroll
    for (int c = 0; c < 8; c++) {
      acc[c] += a0 * BFLO(br[c].x) + a1 * BFHI(br[c].x) +
                a2 * BFLO(br[c].y) + a3 * BFHI(br[c].y) +
                a4 * BFLO(br[c].z) + a5 * BFHI(br[c].z) +
                a6 * BFLO(br[c].w) + a7 * BFHI(br[c].w);
    }
  }

  float lsum = 0.0f;
#pragma unroll
  for (int c = 0; c < 8; c++) {
    int j = tx + 16 * c;
    float t = __expf(0.5f * (Ri[j] - riA)) * acc[c];
    lsum += fmaxf(sqrtf(fmaxf(t, EPSF)) - 0.2f, 0.0f);
  }
  red[tid] = lsum;
  __syncthreads();
  for (int s2 = 128; s2 > 0; s2 >>= 1) {
    if (tid < s2) red[tid] += red[tid + s2];
    __syncthreads();
  }
  if (tid == 0) lsp[cls * 8 + part] = red[0];

  if (part == 0) {
    __syncthreads();
    red[tid] = (tid < 128) ? (float)maskA[tid] : 0.0f;
    __syncthreads();
    for (int s2 = 128; s2 > 0; s2 >>= 1) {
      if (tid < s2) red[tid] += red[tid + s2];
      __syncthreads();
    }
    if (tid == 0) { cnts[cls * 2 + 0] = red[0]; cnts[cls * 2 + 1] = (float)nP; }

    if (tid < nP) {
      float mx = -1e30f;
      for (int q = 0; q < nQ; q++) mx = fmaxf(mx, SMRAW[tid][q]);
      float s = 0.0f;
      for (int q = 0; q < nQ; q++) s += __expf(SMRAW[tid][q] - mx);
      for (int q = 0; q < nQ; q++) SP[tid][q] = __expf(SMRAW[tid][q] - mx) / s;
    }
    if (tid >= 64 && tid < 64 + nQ) {
      int q = tid - 64;
      float mx = -1e30f;
      for (int p = 0; p < nP; p++) mx = fmaxf(mx, SMRAW[p][q]);
      float s = 0.0f;
      for (int p = 0; p < nP; p++) s += __expf(SMRAW[p][q] - mx);
      for (int p = 0; p < nP; p++) SQ[q][p] = __expf(SMRAW[p][q] - mx) / s;
    }
    __syncthreads();
    float lv = 0.0f;
    if (tid < nP * nP) {
      int i = tid / nP, j = tid - i * nP;
      float t = 0.0f;
      for (int l = 0; l < nQ; l++) t += SP[i][l] * SQ[l][j];
      lv = fmaxf(0.5f - sqrtf(fmaxf(t, EPSF)), 0.0f);
    }
    red[tid] = lv;
    __syncthreads();
    for (int s2 = 128; s2 > 0; s2 >>= 1) {
      if (tid < s2) red[tid] += red[tid + s2];
      __syncthreads();
    }
    if (tid == 0) lan[cls] = red[0];
  }
}

__global__ void final_reduce(const float* __restrict__ lsp,
                             const float* __restrict__ lan,
                             const float* __restrict__ cnts,
                             const float* __restrict__ flags,
                             float* __restrict__ out, int n) {
  __shared__ float rl[256], rf[256];
  const int tid = threadIdx.x;
  float lv = 0.0f;
  if (tid < 64) {
    float nA = cnts[tid * 2 + 0];
    float nP = cnts[tid * 2 + 1];
    if (nP > 0.5f && nA > 0.5f) {
      float s = 0.0f;
      for (int p = 0; p < 8; p++) s += lsp[tid * 8 + p];
      float lc = s / (nA * nA) + lan[tid] / (nP * nP);
      lv = nP * lc;
    }
  }
  rl[tid] = lv;
  rf[tid] = flags[tid];
  __syncthreads();
  for (int s2 = 128; s2 > 0; s2 >>= 1) {
    if (tid < s2) { rl[tid] += rl[tid + s2]; rf[tid] += rf[tid + s2]; }
    __syncthreads();
  }
  if (tid == 0) {
    out[0] = rl[0] / (float)n;
    out[1] = rf[0];
  }
}

extern "C" void kernel_launch(void* const* d_in, const int* in_sizes, int n_in,
                              void* d_out, int out_size, void* d_ws,
                              size_t ws_size, hipStream_t stream) {
  const float* feature = (const float*)d_in[0];
  const int* targets = (const int*)d_in[1];
  const int n = in_sizes[1];            // 256
  const int d = in_sizes[0] / n;        // 2048
  const int nn = n * n;
  const size_t small = 512 + 64 + 128 + 256 + (size_t)n * 32;

  int S = 1;
  if (ws_size >= (small + nn + (size_t)16 * nn) * sizeof(float)) S = 16;
  else if (ws_size >= (small + nn + (size_t)4 * nn) * sizeof(float)) S = 4;

  float* ws = (float*)d_ws;
  float* lsp = ws;                 // 512
  float* lan = lsp + 512;          // 64
  float* cnts = lan + 64;          // 128
  float* flags = cnts + 128;       // 256
  float* LSEtab = flags + 256;     // n*32 ([row][id])
  float* G = LSEtab + (size_t)n * 32;   // nn
  float* Gp = (S > 1) ? (G + nn) : G;   // S*nn slices (alias G when S==1)
  float* out = (float*)d_out;

  dim3 gg(n / 64, n / 64, S);
  gemm_tile<<<gg, 256, 0, stream>>>(feature, Gp, n, d, d / S);

  // fused slice-reduce + stats (replaces reduce_slices + old stats)
  stats_kernel<<<n / 4, 256, 0, stream>>>(Gp, targets, G, LSEtab, flags, n, S);

  dim3 gc(64, 8);
  TransitionLoss_30666066494151_kernel<<<gc, 256, 0, stream>>>(
      G, targets, LSEtab, lsp, lan, cnts, n);

  final_reduce<<<1, 256, 0, stream>>>(lsp, lan, cnts, flags, out, n);
}

// Round 24
// 56.270 us; speedup vs baseline: 1.0770x; 1.0770x over previous
//
#include <hip/hip_runtime.h>

#define EPSF 1e-12f

__device__ __forceinline__ unsigned short f2bf(float f) {
  unsigned int u = __float_as_uint(f);
  unsigned int r = u + 0x7fffu + ((u >> 16) & 1u);  // RNE
  return (unsigned short)(r >> 16);
}
#define BFLO(u) __uint_as_float((u) << 16)
#define BFHI(u) __uint_as_float((u) & 0xffff0000u)

// ---------------------------------------------------------------------------
// Kernel 1: partial G slices (split-K). grid (n/64, n/64, S), block 256.
// ---------------------------------------------------------------------------
__global__ void gemm_tile(const float* __restrict__ F, float* __restrict__ Gout,
                          int n, int d, int kchunk) {
  __shared__ float As[64][36];
  __shared__ float Bs[64][36];
  const int tid = threadIdx.x;
  const int bx = blockIdx.x, by = blockIdx.y, kz = blockIdx.z;
  const int ty = tid >> 4, tx = tid & 15;
  const int lrow = tid >> 2;
  const int lcol = (tid & 3) * 8;
  const float* Ap = F + (size_t)(bx * 64 + lrow) * d + (size_t)kz * kchunk + lcol;
  const float* Bp = F + (size_t)(by * 64 + lrow) * d + (size_t)kz * kchunk + lcol;
  float acc[4][4];
  for (int r = 0; r < 4; r++)
    for (int c = 0; c < 4; c++) acc[r][c] = 0.0f;

  for (int ks = 0; ks < kchunk; ks += 32) {
    float4 a0 = *(const float4*)(Ap + ks);
    float4 a1 = *(const float4*)(Ap + ks + 4);
    float4 b0 = *(const float4*)(Bp + ks);
    float4 b1 = *(const float4*)(Bp + ks + 4);
    __syncthreads();
    *(float4*)&As[lrow][lcol]     = a0;
    *(float4*)&As[lrow][lcol + 4] = a1;
    *(float4*)&Bs[lrow][lcol]     = b0;
    *(float4*)&Bs[lrow][lcol + 4] = b1;
    __syncthreads();
#pragma unroll
    for (int kk = 0; kk < 32; kk += 4) {
      float4 av[4], bv[4];
#pragma unroll
      for (int r = 0; r < 4; r++) av[r] = *(const float4*)&As[ty + 16 * r][kk];
#pragma unroll
      for (int c = 0; c < 4; c++) bv[c] = *(const float4*)&Bs[tx + 16 * c][kk];
#pragma unroll
      for (int r = 0; r < 4; r++) {
        float4 A = av[r];
#pragma unroll
        for (int c = 0; c < 4; c++) {
          float4 B = bv[c];
          acc[r][c] += A.x * B.x + A.y * B.y + A.z * B.z + A.w * B.w;
        }
      }
    }
  }
  float* Gs = Gout + (size_t)kz * n * n;
#pragma unroll
  for (int r = 0; r < 4; r++)
#pragma unroll
    for (int c = 0; c < 4; c++)
      Gs[(size_t)(bx * 64 + ty + 16 * r) * n + (by * 64 + tx + 16 * c)] =
          acc[r][c];
}

__global__ void reduce_slices(const float* __restrict__ Gp,
                              float* __restrict__ G, int nn, int nslices) {
  int e = (blockIdx.x * 256 + threadIdx.x) * 4;
  if (e < nn) {
    float4 s = *(const float4*)(Gp + e);
    for (int k = 1; k < nslices; k++) {
      float4 t = *(const float4*)(Gp + (size_t)k * nn + e);
      s.x += t.x; s.y += t.y; s.z += t.z; s.w += t.w;
    }
    *(float4*)(G + e) = s;
  }
}

// ---------------------------------------------------------------------------
// Fused stats kernel: accuracy flags + LSE[r][id] table. grid 64 x 256.
// ---------------------------------------------------------------------------
__global__ void stats_kernel(const float* __restrict__ G,
                             const int* __restrict__ targets,
                             float* __restrict__ LSEtab,
                             float* __restrict__ flags, int n) {
  __shared__ float bins[4][33];
  __shared__ int tg[256];
  __shared__ float diag[256];
  const int tid = threadIdx.x;
  const int lane = tid & 63;
  const int w = tid >> 6;
  tg[tid] = targets[tid];
  diag[tid] = G[(size_t)tid * (n + 1)];
  if (tid < 128) bins[tid >> 5][tid & 31] = 0.0f;
  __syncthreads();

  const int r = blockIdx.x * 4 + w;
  const int nhalf = n >> 1;
  const int opp0 = (r < nhalf) ? nhalf : 0;
  const int myid = tg[r];
  const float sqr = diag[r];

  float4 v = *(const float4*)(G + (size_t)r * n + lane * 4);
  float gv[4] = {v.x, v.y, v.z, v.w};

  float dap = -1e30f, dan = 1e30f;
#pragma unroll
  for (int q = 0; q < 4; q++) {
    int j = lane * 4 + q;
    float dist = sqrtf(fmaxf(sqr + diag[j] - 2.0f * gv[q], EPSF));
    if (tg[j] == myid) dap = fmaxf(dap, dist);
    else               dan = fminf(dan, dist);
  }
#pragma unroll
  for (int off = 32; off; off >>= 1) {
    dap = fmaxf(dap, __shfl_xor(dap, off));
    dan = fminf(dan, __shfl_xor(dan, off));
  }
  if (lane == 0) flags[r] = (dan >= dap) ? 1.0f : 0.0f;

  float mx = -1e30f;
#pragma unroll
  for (int q = 0; q < 4; q++) {
    int j = lane * 4 + q;
    if (j >= opp0 && j < opp0 + nhalf) mx = fmaxf(mx, gv[q]);
  }
#pragma unroll
  for (int off = 32; off; off >>= 1) mx = fmaxf(mx, __shfl_xor(mx, off));

#pragma unroll
  for (int q = 0; q < 4; q++) {
    int j = lane * 4 + q;
    if (j >= opp0 && j < opp0 + nhalf)
      atomicAdd(&bins[w][tg[j]], __expf(gv[q] - mx));
  }
  __syncthreads();

  if (lane < 32) {
    float b = bins[w][lane];
    float lv = __shfl_up(b, 1, 32);
    if (lane == 0) lv = 0.0f;
#pragma unroll
    for (int off = 1; off < 32; off <<= 1) {
      float t = __shfl_up(lv, off, 32);
      if (lane >= off) lv += t;
    }
    float rv = __shfl_down(b, 1, 32);
    if (lane == 31) rv = 0.0f;
#pragma unroll
    for (int off = 1; off < 32; off <<= 1) {
      float t = __shfl_down(rv, off, 32);
      if (lane + off < 32) rv += t;
    }
    float excl = fmaxf(lv + rv, 1e-37f);
    LSEtab[(size_t)r * 32 + lane] = mx + __logf(excl);
  }
}

// ---------------------------------------------------------------------------
// Class-dedup loss kernel. grid (64 classes, 8 row-parts), block 256.
// __launch_bounds__(256,2): independent-register B-column reads (ILP).
// ---------------------------------------------------------------------------
__global__ __launch_bounds__(256, 2) void TransitionLoss_30666066494151_kernel(
    const float* __restrict__ G, const int* __restrict__ targets,
    const float* __restrict__ LSEtab, float* __restrict__ lsp,
    float* __restrict__ lan, float* __restrict__ cnts, int n) {
  __shared__ unsigned short W[128][136];   // 34816 B bf16
  __shared__ int tg[256];
  __shared__ int maskA[128], maskB[128];
  __shared__ float Ri[128], Cl[128];
  __shared__ float SMRAW[16][17];
  __shared__ float SP[16][17], SQ[16][17];
  __shared__ float red[256];
  __shared__ int Plist[16], Qlist[16];
  __shared__ int ctrP, ctrQ;

  const int tid = threadIdx.x;
  const int cls = blockIdx.x;
  const int part = blockIdx.y;      // 0..7 -> rows [part*16, part*16+16)
  const int nhalf = n >> 1;
  const int myid = cls & 31;
  const int hA = cls >> 5;
  const int rowA0 = hA * nhalf;
  const int colB0 = nhalf - rowA0;

  tg[tid] = targets[tid];
  if (tid == 0) { ctrP = 0; ctrQ = 0; }
  __syncthreads();

  if (tid < 128) {
    maskA[tid] = (tg[rowA0 + tid] != myid) ? 1 : 0;
    Ri[tid] = LSEtab[(size_t)(rowA0 + tid) * 32 + myid];
  } else {
    maskB[tid - 128] = (tg[colB0 + tid - 128] != myid) ? 1 : 0;
    Cl[tid - 128] = LSEtab[(size_t)(colB0 + tid - 128) * 32 + myid];
  }
  if (tg[tid] == myid) {
    int inAhalf = (((tid >= nhalf) ? 1 : 0) == hA) ? 1 : 0;
    if (inAhalf) { int k = atomicAdd(&ctrP, 1); if (k < 16) Plist[k] = tid; }
    else         { int k = atomicAdd(&ctrQ, 1); if (k < 16) Qlist[k] = tid; }
  }
  __syncthreads();
  const int nP = min(ctrP, 16), nQ = min(ctrQ, 16);

  // Fused load + W fill (bf16): 16 float4, 8 in flight per group.
#pragma unroll
  for (int k8 = 0; k8 < 2; k8++) {
    float4 g[8];
#pragma unroll
    for (int u = 0; u < 8; u++) {
      int e4 = tid + 256 * (k8 * 8 + u);
      int i = e4 >> 5;
      int l4 = (e4 & 31) << 2;
      g[u] = *(const float4*)(G + (size_t)(rowA0 + i) * n + colB0 + l4);
    }
#pragma unroll
    for (int u = 0; u < 8; u++) {
      int e4 = tid + 256 * (k8 * 8 + u);
      int i = e4 >> 5;
      int l4 = (e4 & 31) << 2;
      float rih = 0.5f * Ri[i];
      int ma = maskA[i];
      float w0 = (ma && maskB[l4 + 0]) ? __expf(g[u].x - rih - 0.5f * Cl[l4 + 0]) : 0.0f;
      float w1 = (ma && maskB[l4 + 1]) ? __expf(g[u].y - rih - 0.5f * Cl[l4 + 1]) : 0.0f;
      float w2 = (ma && maskB[l4 + 2]) ? __expf(g[u].z - rih - 0.5f * Cl[l4 + 2]) : 0.0f;
      float w3 = (ma && maskB[l4 + 3]) ? __expf(g[u].w - rih - 0.5f * Cl[l4 + 3]) : 0.0f;
      uint2 packed;
      packed.x = (unsigned)f2bf(w0) | ((unsigned)f2bf(w1) << 16);
      packed.y = (unsigned)f2bf(w2) | ((unsigned)f2bf(w3) << 16);
      *(uint2*)&W[i][l4] = packed;
    }
  }

  // t_pos parallel gather (part 0 only): one latency round.
  if (part == 0) {
    int p = tid >> 4, q = tid & 15;
    float v = 0.0f;
    if (p < nP && q < nQ) v = G[(size_t)Plist[p] * n + Qlist[q]];
    SMRAW[p][q] = v;
  }
  __syncthreads();

  // SYRK: rows [part*16 .. +16) x 128 cols, K=128 bf16 from LDS.
  // All 8 B-reads issued into independent registers BEFORE any unpack/FMA.
  const int i0 = part * 16;
  const int ty = tid >> 4, tx = tid & 15;
  const float riA = Ri[i0 + ty];
  float acc[8];
#pragma unroll
  for (int c = 0; c < 8; c++) acc[c] = 0.0f;

  for (int kk = 0; kk < 128; kk += 8) {
    uint4 ar = *(const uint4*)&W[i0 + ty][kk];
    uint4 br[8];
#pragma unroll
    for (int c = 0; c < 8; c++) br[c] = *(const uint4*)&W[tx + 16 * c][kk];
    float a0 = BFLO(ar.x), a1 = BFHI(ar.x), a2 = BFLO(ar.y), a3 = BFHI(ar.y);
    float a4 = BFLO(ar.z), a5 = BFHI(ar.z), a6 = BFLO(ar.w), a7 = BFHI(ar.w);
#pragma unroll
    for (int c = 0; c < 8; c++) {
      acc[c] += a0 * BFLO(br[c].x) + a1 * BFHI(br[c].x) +
                a2 * BFLO(br[c].y) + a3 * BFHI(br[c].y) +
                a4 * BFLO(br[c].z) + a5 * BFHI(br[c].z) +
                a6 * BFLO(br[c].w) + a7 * BFHI(br[c].w);
    }
  }

  float lsum = 0.0f;
#pragma unroll
  for (int c = 0; c < 8; c++) {
    int j = tx + 16 * c;
    float t = __expf(0.5f * (Ri[j] - riA)) * acc[c];
    lsum += fmaxf(sqrtf(fmaxf(t, EPSF)) - 0.2f, 0.0f);
  }
  red[tid] = lsum;
  __syncthreads();
  for (int s2 = 128; s2 > 0; s2 >>= 1) {
    if (tid < s2) red[tid] += red[tid + s2];
    __syncthreads();
  }
  if (tid == 0) lsp[cls * 8 + part] = red[0];

  if (part == 0) {
    __syncthreads();
    red[tid] = (tid < 128) ? (float)maskA[tid] : 0.0f;
    __syncthreads();
    for (int s2 = 128; s2 > 0; s2 >>= 1) {
      if (tid < s2) red[tid] += red[tid + s2];
      __syncthreads();
    }
    if (tid == 0) { cnts[cls * 2 + 0] = red[0]; cnts[cls * 2 + 1] = (float)nP; }

    if (tid < nP) {
      float mx = -1e30f;
      for (int q = 0; q < nQ; q++) mx = fmaxf(mx, SMRAW[tid][q]);
      float s = 0.0f;
      for (int q = 0; q < nQ; q++) s += __expf(SMRAW[tid][q] - mx);
      for (int q = 0; q < nQ; q++) SP[tid][q] = __expf(SMRAW[tid][q] - mx) / s;
    }
    if (tid >= 64 && tid < 64 + nQ) {
      int q = tid - 64;
      float mx = -1e30f;
      for (int p = 0; p < nP; p++) mx = fmaxf(mx, SMRAW[p][q]);
      float s = 0.0f;
      for (int p = 0; p < nP; p++) s += __expf(SMRAW[p][q] - mx);
      for (int p = 0; p < nP; p++) SQ[q][p] = __expf(SMRAW[p][q] - mx) / s;
    }
    __syncthreads();
    float lv = 0.0f;
    if (tid < nP * nP) {
      int i = tid / nP, j = tid - i * nP;
      float t = 0.0f;
      for (int l = 0; l < nQ; l++) t += SP[i][l] * SQ[l][j];
      lv = fmaxf(0.5f - sqrtf(fmaxf(t, EPSF)), 0.0f);
    }
    red[tid] = lv;
    __syncthreads();
    for (int s2 = 128; s2 > 0; s2 >>= 1) {
      if (tid < s2) red[tid] += red[tid + s2];
      __syncthreads();
    }
    if (tid == 0) lan[cls] = red[0];
  }
}

__global__ void final_reduce(const float* __restrict__ lsp,
                             const float* __restrict__ lan,
                             const float* __restrict__ cnts,
                             const float* __restrict__ flags,
                             float* __restrict__ out, int n) {
  __shared__ float rl[256], rf[256];
  const int tid = threadIdx.x;
  float lv = 0.0f;
  if (tid < 64) {
    float nA = cnts[tid * 2 + 0];
    float nP = cnts[tid * 2 + 1];
    if (nP > 0.5f && nA > 0.5f) {
      float s = 0.0f;
      for (int p = 0; p < 8; p++) s += lsp[tid * 8 + p];
      float lc = s / (nA * nA) + lan[tid] / (nP * nP);
      lv = nP * lc;
    }
  }
  rl[tid] = lv;
  rf[tid] = flags[tid];
  __syncthreads();
  for (int s2 = 128; s2 > 0; s2 >>= 1) {
    if (tid < s2) { rl[tid] += rl[tid + s2]; rf[tid] += rf[tid + s2]; }
    __syncthreads();
  }
  if (tid == 0) {
    out[0] = rl[0] / (float)n;
    out[1] = rf[0];
  }
}

extern "C" void kernel_launch(void* const* d_in, const int* in_sizes, int n_in,
                              void* d_out, int out_size, void* d_ws,
                              size_t ws_size, hipStream_t stream) {
  const float* feature = (const float*)d_in[0];
  const int* targets = (const int*)d_in[1];
  const int n = in_sizes[1];            // 256
  const int d = in_sizes[0] / n;        // 2048
  const int nn = n * n;
  const size_t small = 512 + 64 + 128 + 256 + (size_t)n * 32;

  int S = 1;
  if (ws_size >= (small + nn + (size_t)16 * nn) * sizeof(float)) S = 16;
  else if (ws_size >= (small + nn + (size_t)4 * nn) * sizeof(float)) S = 4;

  float* ws = (float*)d_ws;
  float* lsp = ws;                 // 512
  float* lan = lsp + 512;          // 64
  float* cnts = lan + 64;          // 128
  float* flags = cnts + 128;       // 256
  float* LSEtab = flags + 256;     // n*32
  float* G = LSEtab + (size_t)n * 32;   // nn
  float* Gp = (S > 1) ? (G + nn) : G;
  float* out = (float*)d_out;

  dim3 gg(n / 64, n / 64, S);
  gemm_tile<<<gg, 256, 0, stream>>>(feature, Gp, n, d, d / S);
  if (S > 1)
    reduce_slices<<<(nn + 1023) / 1024, 256, 0, stream>>>(Gp, G, nn, S);

  stats_kernel<<<n / 4, 256, 0, stream>>>(G, targets, LSEtab, flags, n);

  dim3 gc(64, 8);
  TransitionLoss_30666066494151_kernel<<<gc, 256, 0, stream>>>(
      G, targets, LSEtab, lsp, lan, cnts, n);

  final_reduce<<<1, 256, 0, stream>>>(lsp, lan, cnts, flags, out, n);
}